// Round 6
// baseline (829.472 us; speedup 1.0000x reference)
//
#include <hip/hip_runtime.h>
#include <hip/hip_bf16.h>
#include <math.h>

// Problem constants (fixed by setup_inputs)
#define M_TOTAL 6272   // B*P
#define N_CS    16384  // coreset rows
#define D_DIM   384
#define BATCH   8
#define P_PATCH 784
#define KNN     9

// MFMA GEMM tiling: 128x256 tile, 4 waves (2x2 of 64x128), BK=64
#define MTILES  (M_TOTAL / 128)  // 49
#define NTILES2 (N_CS / 256)     // 64 -> pvals[m][64]

typedef _Float16 half8 __attribute__((ext_vector_type(8)));
typedef float    floatx4 __attribute__((ext_vector_type(4)));

// async global->LDS, 16B per lane; LDS dest must be uniform-base + lane*16
__device__ __forceinline__ void async_copy16(const void* g, void* l) {
    __builtin_amdgcn_global_load_lds(
        (const __attribute__((address_space(1))) void*)g,
        (__attribute__((address_space(3))) void*)l, 16, 0, 0);
}

// ---------------- convert fp32->f16, fused cs+emb (wave per row) ----------
// rows [0, N_CS) -> cs (+cnorm), rows [N_CS, N_CS+M_TOTAL) -> emb.
// Also zero-inits the 8 packed argmax slots (ws is poisoned 0xAA).
__global__ void convert_all_kernel(const float* __restrict__ emb,
                                   const float* __restrict__ cs,
                                   _Float16* __restrict__ embh,
                                   _Float16* __restrict__ csh,
                                   float* __restrict__ cnorm,
                                   unsigned long long* __restrict__ packed) {
    if (blockIdx.x == 0 && threadIdx.x < BATCH) packed[threadIdx.x] = 0ull;
    int w = threadIdx.x >> 6, lane = threadIdx.x & 63;
    int row = blockIdx.x * 4 + w;
    if (row >= N_CS + M_TOTAL) return;
    bool is_cs = row < N_CS;
    const float* r = (is_cs ? cs + (size_t)row * D_DIM
                            : emb + (size_t)(row - N_CS) * D_DIM) + lane * 6;
    float2 a = *(const float2*)r;
    float2 b = *(const float2*)(r + 2);
    float2 c = *(const float2*)(r + 4);
    union { _Float16 h[2]; unsigned u; } p0, p1, p2;
    p0.h[0] = (_Float16)a.x; p0.h[1] = (_Float16)a.y;
    p1.h[0] = (_Float16)b.x; p1.h[1] = (_Float16)b.y;
    p2.h[0] = (_Float16)c.x; p2.h[1] = (_Float16)c.y;
    unsigned* dst = (unsigned*)(is_cs ? csh + (size_t)row * D_DIM
                                      : embh + (size_t)(row - N_CS) * D_DIM) + lane * 3;
    dst[0] = p0.u; dst[1] = p1.u; dst[2] = p2.u;
    if (is_cs) {
        float s = a.x * a.x + a.y * a.y + b.x * b.x + b.y * b.y + c.x * c.x + c.y * c.y;
#pragma unroll
        for (int mk = 1; mk <= 32; mk <<= 1) s += __shfl_xor(s, mk, 64);
        if (lane == 0) cnorm[row] = s;
    }
}

// --------------------------------------------- MFMA GEMM + min/argmin ----
// 1-D grid 3136; XCD-aware remap: xcd = b&7 owns y in [xcd*8, xcd*8+8),
// x = b>>6 varies slowest -> each XCD keeps its 1.5 MB B-set L2-resident
// and reuses each 96 KB A-tile 8x back-to-back. (R5: FETCH 191 MB = 11x
// over-fetch -> L2-miss latency on every staging drain.)
// LDS XOR-swizzled (R5: conflicts 2.2e7 -> 1.2e4). 3 blocks/CU (144 KB LDS).
__global__ __launch_bounds__(256, 3) void mindist_mfma_kernel(
    const _Float16* __restrict__ embh, const _Float16* __restrict__ csh,
    const float* __restrict__ cnorm,
    float* __restrict__ pvals, int* __restrict__ pidx) {
    __shared__ _Float16 As[128 * 64];   // 16 KB
    __shared__ _Float16 Bs[256 * 64];   // 32 KB

    const int b    = blockIdx.x;
    const int bx   = b >> 6;                               // 0..48
    const int by   = ((b & 7) << 3) | ((b >> 3) & 7);      // 0..63 (XCD-major)
    const int tid  = threadIdx.x;
    const int lane = tid & 63;
    const int w    = tid >> 6;
    const int wr   = w >> 1, wc = w & 1;
    const int row0  = bx * 128;
    const int cbase = by * 256;
    const int q   = lane >> 4;
    const int cl  = lane & 15;
    const int cl7 = cl & 7;

    floatx4 acc[4][8];
#pragma unroll
    for (int mi = 0; mi < 4; ++mi)
#pragma unroll
        for (int nj = 0; nj < 8; ++nj) acc[mi][nj] = (floatx4){0.f, 0.f, 0.f, 0.f};

    float cn_l[8];
#pragma unroll
    for (int nj = 0; nj < 8; ++nj)
        cn_l[nj] = cnorm[cbase + wc * 128 + nj * 16 + cl];

    const int sub = lane >> 3;          // row within 8-row staging block
    const int gch = (lane & 7) ^ sub;   // swizzled source 16B-chunk
    const int kb  = gch * 8;            // element offset

    for (int kk = 0; kk < D_DIM; kk += 64) {
        __syncthreads();
#pragma unroll
        for (int i = 0; i < 12; ++i) {
            int inst = w * 12 + i;      // wave-uniform: 0..47 (16 A + 32 B)
            if (inst < 16) {
                int r = inst * 8 + sub;
                async_copy16(embh + (size_t)(row0 + r) * D_DIM + kk + kb,
                             &As[inst * 512 + lane * 8]);
            } else {
                int blk = inst - 16;
                int r = blk * 8 + sub;
                async_copy16(csh + (size_t)(cbase + r) * D_DIM + kk + kb,
                             &Bs[blk * 512 + lane * 8]);
            }
        }
        __syncthreads();
#pragma unroll
        for (int ks = 0; ks < 64; ks += 32) {
            const int ks8 = ks >> 3;
            half8 af[4], bf[8];
#pragma unroll
            for (int mi = 0; mi < 4; ++mi)
                af[mi] = *(const half8*)&As[(wr * 64 + mi * 16 + cl) * 64
                                            + (((ks8 + q) ^ cl7) * 8)];
#pragma unroll
            for (int nj = 0; nj < 8; ++nj)
                bf[nj] = *(const half8*)&Bs[(wc * 128 + nj * 16 + cl) * 64
                                            + (((ks8 + q) ^ cl7) * 8)];
#pragma unroll
            for (int mi = 0; mi < 4; ++mi)
#pragma unroll
                for (int nj = 0; nj < 8; ++nj)
                    acc[mi][nj] = __builtin_amdgcn_mfma_f32_16x16x32_f16(
                        af[mi], bf[nj], acc[mi][nj], 0, 0, 0);
        }
    }

    // epilogue: per-row min/argmin over the 256-wide tile
    __syncthreads();
    float* smv = (float*)As;            // [128][2]
    int*   smi = (int*)(As + 512);      // 1 KB past smv

#pragma unroll
    for (int mi = 0; mi < 4; ++mi) {
#pragma unroll
        for (int r = 0; r < 4; ++r) {
            float v = 3.4e38f; int idx = 0x7fffffff;
#pragma unroll
            for (int nj = 0; nj < 8; ++nj) {   // ascending col per lane, strict <
                float d = cn_l[nj] - 2.f * acc[mi][nj][r];
                int   c = cbase + wc * 128 + nj * 16 + cl;
                if (d < v) { v = d; idx = c; }
            }
#pragma unroll
            for (int mk = 1; mk <= 8; mk <<= 1) {
                float v2 = __shfl_xor(v, mk, 64);
                int   i2 = __shfl_xor(idx, mk, 64);
                if (v2 < v || (v2 == v && i2 < idx)) { v = v2; idx = i2; }
            }
            if (cl == 0) {
                int rl = wr * 64 + mi * 16 + q * 4 + r;
                smv[rl * 2 + wc] = v;
                smi[rl * 2 + wc] = idx;
            }
        }
    }
    __syncthreads();
    if (tid < 128) {
        float v = smv[tid * 2];      int i = smi[tid * 2];
        float v1 = smv[tid * 2 + 1]; int i1 = smi[tid * 2 + 1];
        if (v1 < v) { v = v1; i = i1; }   // wc0 indices always < wc1 indices
        pvals[(size_t)(row0 + tid) * NTILES2 + by] = v;
        pidx[(size_t)(row0 + tid) * NTILES2 + by]  = i;
    }
}

// ---- partial-min reduce + EXACT fp32 rescore + fused batch-argmax -------
// packed key: (score_bits << 32) | (0x7fffffff - patch): atomicMax gives
// max score, ties -> smaller patch index (JAX argmax semantics).
__global__ void reduce_rescore_kernel(const float* __restrict__ pvals,
                                      const int* __restrict__ pidx,
                                      const float* __restrict__ emb,
                                      const float* __restrict__ cs,
                                      float* __restrict__ scores,
                                      int* __restrict__ loc,
                                      unsigned long long* __restrict__ packed) {
    int w = threadIdx.x >> 6, lane = threadIdx.x & 63;
    int m = blockIdx.x * 4 + w;
    float v = pvals[(size_t)m * NTILES2 + lane];
    int   i = pidx[(size_t)m * NTILES2 + lane];
#pragma unroll
    for (int mk = 1; mk <= 32; mk <<= 1) {
        float v2 = __shfl_xor(v, mk, 64);
        int   i2 = __shfl_xor(i, mk, 64);
        if (v2 < v || (v2 == v && i2 < i)) { v = v2; i = i2; }
    }
    // exact fp32 distance to the selected coreset row
    const float* a = emb + (size_t)m * D_DIM;
    const float* b = cs + (size_t)i * D_DIM;
    float s = 0.f;
#pragma unroll
    for (int t = 0; t < D_DIM / 64; ++t) {
        float d = a[lane + t * 64] - b[lane + t * 64];
        s += d * d;
    }
#pragma unroll
    for (int mk = 1; mk <= 32; mk <<= 1) s += __shfl_xor(s, mk, 64);
    if (lane == 0) {
        float sc = sqrtf(s);
        scores[m] = sc;
        loc[m] = i;
        int bb = m / P_PATCH, p = m % P_PATCH;
        unsigned long long key =
            ((unsigned long long)__float_as_uint(sc) << 32) |
            (unsigned)(0x7fffffff - p);
        atomicMax(&packed[bb], key);
    }
}

// -------------------- d_nn: 8 queries x 16384 coreset (coalesced GEMV) ----
__global__ void dnn_kernel(const float* __restrict__ cs,
                           const float* __restrict__ cnorm,
                           const unsigned long long* __restrict__ packed,
                           const int* __restrict__ loc,
                           float* __restrict__ dmat) {
    int lane = threadIdx.x & 63;
    int gw = (blockIdx.x * 256 + threadIdx.x) >> 6;  // 0..1023
    float qv[BATCH][6];
#pragma unroll
    for (int b = 0; b < BATCH; ++b) {
        int p  = 0x7fffffff - (unsigned)(packed[b] & 0xffffffffull);
        int nn = loc[b * P_PATCH + p];
        const float* qr = cs + (size_t)nn * D_DIM + lane * 6;
#pragma unroll
        for (int j = 0; j < 6; ++j) qv[b][j] = qr[j];
    }
    for (int n = gw; n < N_CS; n += 1024) {
        const float* r = cs + (size_t)n * D_DIM + lane * 6;
        float x[6];
#pragma unroll
        for (int j = 0; j < 6; ++j) x[j] = r[j];
        float s[BATCH];
#pragma unroll
        for (int b = 0; b < BATCH; ++b) {
            float t = 0.f;
#pragma unroll
            for (int j = 0; j < 6; ++j) t += x[j] * qv[b][j];
            s[b] = t;
        }
#pragma unroll
        for (int b = 0; b < BATCH; ++b)
#pragma unroll
            for (int mk = 1; mk <= 32; mk <<= 1) s[b] += __shfl_xor(s[b], mk, 64);
        if (lane < BATCH) {
            float sv = s[0];
#pragma unroll
            for (int b = 1; b < BATCH; ++b) sv = (lane == b) ? s[b] : sv;
            dmat[(size_t)lane * N_CS + n] = cnorm[n] - 2.f * sv;  // -qnorm shift: order-safe
        }
    }
}

// ----------------------- top-9 merge + exact dsup + softmax weighting ----
__device__ inline void merge9(float* av, int* ai, const float* bv, const int* bi) {
    float mv[KNN]; int mi[KNN];
    int x = 0, y = 0;
#pragma unroll
    for (int k = 0; k < KNN; ++k) {
        bool ta = (av[x] < bv[y]) || (av[x] == bv[y] && ai[x] < bi[y]);
        if (ta) { mv[k] = av[x]; mi[k] = ai[x]; ++x; }
        else    { mv[k] = bv[y]; mi[k] = bi[y]; ++y; }
    }
#pragma unroll
    for (int k = 0; k < KNN; ++k) { av[k] = mv[k]; ai[k] = mi[k]; }
}

__global__ void top9_final_kernel(const float* __restrict__ dmat,
                                  const float* __restrict__ emb,
                                  const float* __restrict__ cs,
                                  const unsigned long long* __restrict__ packed,
                                  float* __restrict__ out) {
    int b = blockIdx.x;
    int tid = threadIdx.x;  // 512
    __shared__ float lv[512][KNN];
    __shared__ int   li[512][KNN];
    __shared__ float mf[D_DIM];
    __shared__ float dsup[KNN];

    unsigned long long key = packed[b];
    int   mp     = 0x7fffffff - (unsigned)(key & 0xffffffffull);
    float bscore = __uint_as_float((unsigned)(key >> 32));
    const float* frow = emb + (size_t)(b * P_PATCH + mp) * D_DIM;
    for (int i = tid; i < D_DIM; i += 512) mf[i] = frow[i];

    float tv[KNN]; int ti[KNN];
#pragma unroll
    for (int k = 0; k < KNN; ++k) { tv[k] = 3.4e38f; ti[k] = 0x7fffffff; }
    for (int n = tid; n < N_CS; n += 512) {   // ascending n per thread
        float d = dmat[(size_t)b * N_CS + n];
        if (d < tv[KNN - 1] || (d == tv[KNN - 1] && n < ti[KNN - 1])) {
            tv[KNN - 1] = d; ti[KNN - 1] = n;
#pragma unroll
            for (int k = KNN - 1; k > 0; --k) {
                if (tv[k] < tv[k - 1] || (tv[k] == tv[k - 1] && ti[k] < ti[k - 1])) {
                    float fv = tv[k]; tv[k] = tv[k - 1]; tv[k - 1] = fv;
                    int   iv = ti[k]; ti[k] = ti[k - 1]; ti[k - 1] = iv;
                }
            }
        }
    }
#pragma unroll
    for (int k = 0; k < KNN; ++k) { lv[tid][k] = tv[k]; li[tid][k] = ti[k]; }
    __syncthreads();
    for (int off = 256; off > 0; off >>= 1) {
        if (tid < off) {
            float av[KNN]; int ai[KNN]; float bv2[KNN]; int bi2[KNN];
#pragma unroll
            for (int k = 0; k < KNN; ++k) {
                av[k]  = lv[tid][k];        ai[k]  = li[tid][k];
                bv2[k] = lv[tid + off][k];  bi2[k] = li[tid + off][k];
            }
            merge9(av, ai, bv2, bi2);
#pragma unroll
            for (int k = 0; k < KNN; ++k) { lv[tid][k] = av[k]; li[tid][k] = ai[k]; }
        }
        __syncthreads();
    }
    // exact fp32 distances to the 9 support rows: 32 lanes per neighbor
    {
        int k      = tid >> 5;   // 0..15
        int lane32 = tid & 31;
        if (k < KNN) {
            int idx = li[0][k];
            const float* r = cs + (size_t)idx * D_DIM;
            float s = 0.f;
            for (int i = lane32; i < D_DIM; i += 32) {
                float df = mf[i] - r[i];
                s += df * df;
            }
#pragma unroll
            for (int mk = 1; mk <= 16; mk <<= 1) s += __shfl_xor(s, mk, 64);
            if (lane32 == 0) dsup[k] = sqrtf(fmaxf(s, 0.f));
        }
    }
    __syncthreads();
    if (tid == 0) {
        float mx = dsup[0];
        for (int k = 1; k < KNN; ++k) mx = fmaxf(mx, dsup[k]);
        float sum = 0.f, e0 = 0.f;
        for (int k = 0; k < KNN; ++k) {
            float e = expf(dsup[k] - mx);
            sum += e;
            if (k == 0) e0 = e;
        }
        out[b] = (1.f - e0 / sum) * bscore;
    }
}

// ------------------------------------------------------------- launcher ----
extern "C" void kernel_launch(void* const* d_in, const int* in_sizes, int n_in,
                              void* d_out, int out_size, void* d_ws, size_t ws_size,
                              hipStream_t stream) {
    (void)in_sizes; (void)n_in; (void)out_size; (void)ws_size;
    const float* emb = (const float*)d_in[0];
    const float* cs  = (const float*)d_in[1];
    float* out = (float*)d_out;

    // workspace layout
    char* p = (char*)d_ws;
    float* cnorm  = (float*)p;  p += (size_t)N_CS * 4;                     // 64 KB
    float* pvals  = (float*)p;  p += (size_t)M_TOTAL * NTILES2 * 4;        // 1.6 MB
    int*   pidx   = (int*)p;    p += (size_t)M_TOTAL * NTILES2 * 4;        // 1.6 MB
    float* scores = (float*)p;  p += (size_t)M_TOTAL * 4;
    int*   loc    = (int*)p;    p += (size_t)M_TOTAL * 4;
    p = (char*)(((size_t)p + 7) & ~(size_t)7);
    unsigned long long* packed = (unsigned long long*)p; p += BATCH * 8;
    float* dmat   = (float*)p;  p += (size_t)BATCH * N_CS * 4;             // 512 KB
    p = (char*)(((size_t)p + 15) & ~(size_t)15);
    _Float16* embh = (_Float16*)p; p += (size_t)M_TOTAL * D_DIM * 2;       // 4.8 MB
    _Float16* csh  = (_Float16*)p; p += (size_t)N_CS * D_DIM * 2;          // 12.6 MB

    {
        int rows = N_CS + M_TOTAL;
        convert_all_kernel<<<(rows + 3) / 4, 256, 0, stream>>>(emb, cs, embh, csh,
                                                               cnorm, packed);
    }
    mindist_mfma_kernel<<<MTILES * NTILES2, 256, 0, stream>>>(embh, csh, cnorm,
                                                              pvals, pidx);
    reduce_rescore_kernel<<<M_TOTAL / 4, 256, 0, stream>>>(pvals, pidx, emb, cs,
                                                           scores, loc, packed);
    dnn_kernel<<<256, 256, 0, stream>>>(cs, cnorm, packed, loc, dmat);
    top9_final_kernel<<<BATCH, 512, 0, stream>>>(dmat, emb, cs, packed, out);
}

// Round 7
// 361.982 us; speedup vs baseline: 2.2915x; 2.2915x over previous
//
#include <hip/hip_runtime.h>
#include <hip/hip_bf16.h>
#include <math.h>

// Problem constants (fixed by setup_inputs)
#define M_TOTAL 6272   // B*P
#define N_CS    16384  // coreset rows
#define D_DIM   384
#define BATCH   8
#define P_PATCH 784
#define KNN     9

// MFMA GEMM tiling: 128x256 tile, 4 waves (2x2 of 64x128), BK=64
#define MTILES  (M_TOTAL / 128)  // 49
#define NTILES2 (N_CS / 256)     // 64 -> pvals[m][64]

typedef _Float16 half8 __attribute__((ext_vector_type(8)));
typedef float    floatx4 __attribute__((ext_vector_type(4)));

// async global->LDS, 16B per lane; LDS dest must be uniform-base + lane*16
__device__ __forceinline__ void async_copy16(const void* g, void* l) {
    __builtin_amdgcn_global_load_lds(
        (const __attribute__((address_space(1))) void*)g,
        (__attribute__((address_space(3))) void*)l, 16, 0, 0);
}

// ---------------- convert fp32->f16, fused cs+emb (wave per row) ----------
// rows [0, N_CS) -> cs (+cnorm), rows [N_CS, N_CS+M_TOTAL) -> emb.
// Also zero-inits the 8 packed argmax slots (ws is poisoned 0xAA).
__global__ void convert_all_kernel(const float* __restrict__ emb,
                                   const float* __restrict__ cs,
                                   _Float16* __restrict__ embh,
                                   _Float16* __restrict__ csh,
                                   float* __restrict__ cnorm,
                                   unsigned long long* __restrict__ packed) {
    if (blockIdx.x == 0 && threadIdx.x < BATCH) packed[threadIdx.x] = 0ull;
    int w = threadIdx.x >> 6, lane = threadIdx.x & 63;
    int row = blockIdx.x * 4 + w;
    if (row >= N_CS + M_TOTAL) return;
    bool is_cs = row < N_CS;
    const float* r = (is_cs ? cs + (size_t)row * D_DIM
                            : emb + (size_t)(row - N_CS) * D_DIM) + lane * 6;
    float2 a = *(const float2*)r;
    float2 b = *(const float2*)(r + 2);
    float2 c = *(const float2*)(r + 4);
    union { _Float16 h[2]; unsigned u; } p0, p1, p2;
    p0.h[0] = (_Float16)a.x; p0.h[1] = (_Float16)a.y;
    p1.h[0] = (_Float16)b.x; p1.h[1] = (_Float16)b.y;
    p2.h[0] = (_Float16)c.x; p2.h[1] = (_Float16)c.y;
    unsigned* dst = (unsigned*)(is_cs ? csh + (size_t)row * D_DIM
                                      : embh + (size_t)(row - N_CS) * D_DIM) + lane * 3;
    dst[0] = p0.u; dst[1] = p1.u; dst[2] = p2.u;
    if (is_cs) {
        float s = a.x * a.x + a.y * a.y + b.x * b.x + b.y * b.y + c.x * c.x + c.y * c.y;
#pragma unroll
        for (int mk = 1; mk <= 32; mk <<= 1) s += __shfl_xor(s, mk, 64);
        if (lane == 0) cnorm[row] = s;
    }
}

// --------------------------------------------- MFMA GEMM + min/argmin ----
// 1-D grid 3136; XCD-aware remap: xcd = b&7 owns y in [xcd*8, xcd*8+8),
// x = b>>6 varies slowest -> each XCD keeps its 1.5 MB B-set L2-resident
// and reuses each 96 KB A-tile 8x back-to-back.
// LDS XOR-swizzled (R5: conflicts 2.2e7 -> 1.2e4).
// __launch_bounds__(256,2): DO NOT raise to 3 — R6 showed the allocator
// drops to 84 VGPR and spills acc[4][8] (WRITE 1.4 GB, 612 us). LDS
// (48 KB) already caps occupancy at 3 blocks/CU; VGPR=128 allows 4, so
// (256,2) loses nothing.
__global__ __launch_bounds__(256, 2) void mindist_mfma_kernel(
    const _Float16* __restrict__ embh, const _Float16* __restrict__ csh,
    const float* __restrict__ cnorm,
    float* __restrict__ pvals, int* __restrict__ pidx) {
    __shared__ _Float16 As[128 * 64];   // 16 KB
    __shared__ _Float16 Bs[256 * 64];   // 32 KB

    const int b    = blockIdx.x;
    const int bx   = b >> 6;                               // 0..48
    const int by   = ((b & 7) << 3) | ((b >> 3) & 7);      // 0..63 (XCD-major)
    const int tid  = threadIdx.x;
    const int lane = tid & 63;
    const int w    = tid >> 6;
    const int wr   = w >> 1, wc = w & 1;
    const int row0  = bx * 128;
    const int cbase = by * 256;
    const int q   = lane >> 4;
    const int cl  = lane & 15;
    const int cl7 = cl & 7;

    floatx4 acc[4][8];
#pragma unroll
    for (int mi = 0; mi < 4; ++mi)
#pragma unroll
        for (int nj = 0; nj < 8; ++nj) acc[mi][nj] = (floatx4){0.f, 0.f, 0.f, 0.f};

    float cn_l[8];
#pragma unroll
    for (int nj = 0; nj < 8; ++nj)
        cn_l[nj] = cnorm[cbase + wc * 128 + nj * 16 + cl];

    const int sub = lane >> 3;          // row within 8-row staging block
    const int gch = (lane & 7) ^ sub;   // swizzled source 16B-chunk
    const int kb  = gch * 8;            // element offset

    for (int kk = 0; kk < D_DIM; kk += 64) {
        __syncthreads();
#pragma unroll
        for (int i = 0; i < 12; ++i) {
            int inst = w * 12 + i;      // wave-uniform: 0..47 (16 A + 32 B)
            if (inst < 16) {
                int r = inst * 8 + sub;
                async_copy16(embh + (size_t)(row0 + r) * D_DIM + kk + kb,
                             &As[inst * 512 + lane * 8]);
            } else {
                int blk = inst - 16;
                int r = blk * 8 + sub;
                async_copy16(csh + (size_t)(cbase + r) * D_DIM + kk + kb,
                             &Bs[blk * 512 + lane * 8]);
            }
        }
        __syncthreads();
#pragma unroll
        for (int ks = 0; ks < 64; ks += 32) {
            const int ks8 = ks >> 3;
            half8 af[4], bf[8];
#pragma unroll
            for (int mi = 0; mi < 4; ++mi)
                af[mi] = *(const half8*)&As[(wr * 64 + mi * 16 + cl) * 64
                                            + (((ks8 + q) ^ cl7) * 8)];
#pragma unroll
            for (int nj = 0; nj < 8; ++nj)
                bf[nj] = *(const half8*)&Bs[(wc * 128 + nj * 16 + cl) * 64
                                            + (((ks8 + q) ^ cl7) * 8)];
#pragma unroll
            for (int mi = 0; mi < 4; ++mi)
#pragma unroll
                for (int nj = 0; nj < 8; ++nj)
                    acc[mi][nj] = __builtin_amdgcn_mfma_f32_16x16x32_f16(
                        af[mi], bf[nj], acc[mi][nj], 0, 0, 0);
        }
    }

    // epilogue: per-row min/argmin over the 256-wide tile
    __syncthreads();
    float* smv = (float*)As;            // [128][2]
    int*   smi = (int*)(As + 512);      // 1 KB past smv

#pragma unroll
    for (int mi = 0; mi < 4; ++mi) {
#pragma unroll
        for (int r = 0; r < 4; ++r) {
            float v = 3.4e38f; int idx = 0x7fffffff;
#pragma unroll
            for (int nj = 0; nj < 8; ++nj) {   // ascending col per lane, strict <
                float d = cn_l[nj] - 2.f * acc[mi][nj][r];
                int   c = cbase + wc * 128 + nj * 16 + cl;
                if (d < v) { v = d; idx = c; }
            }
#pragma unroll
            for (int mk = 1; mk <= 8; mk <<= 1) {
                float v2 = __shfl_xor(v, mk, 64);
                int   i2 = __shfl_xor(idx, mk, 64);
                if (v2 < v || (v2 == v && i2 < idx)) { v = v2; idx = i2; }
            }
            if (cl == 0) {
                int rl = wr * 64 + mi * 16 + q * 4 + r;
                smv[rl * 2 + wc] = v;
                smi[rl * 2 + wc] = idx;
            }
        }
    }
    __syncthreads();
    if (tid < 128) {
        float v = smv[tid * 2];      int i = smi[tid * 2];
        float v1 = smv[tid * 2 + 1]; int i1 = smi[tid * 2 + 1];
        if (v1 < v) { v = v1; i = i1; }   // wc0 indices always < wc1 indices
        pvals[(size_t)(row0 + tid) * NTILES2 + by] = v;
        pidx[(size_t)(row0 + tid) * NTILES2 + by]  = i;
    }
}

// ---- partial-min reduce + EXACT fp32 rescore + fused batch-argmax -------
// packed key: (score_bits << 32) | (0x7fffffff - patch): atomicMax gives
// max score, ties -> smaller patch index (JAX argmax semantics).
__global__ void reduce_rescore_kernel(const float* __restrict__ pvals,
                                      const int* __restrict__ pidx,
                                      const float* __restrict__ emb,
                                      const float* __restrict__ cs,
                                      float* __restrict__ scores,
                                      int* __restrict__ loc,
                                      unsigned long long* __restrict__ packed) {
    int w = threadIdx.x >> 6, lane = threadIdx.x & 63;
    int m = blockIdx.x * 4 + w;
    float v = pvals[(size_t)m * NTILES2 + lane];
    int   i = pidx[(size_t)m * NTILES2 + lane];
#pragma unroll
    for (int mk = 1; mk <= 32; mk <<= 1) {
        float v2 = __shfl_xor(v, mk, 64);
        int   i2 = __shfl_xor(i, mk, 64);
        if (v2 < v || (v2 == v && i2 < i)) { v = v2; i = i2; }
    }
    // exact fp32 distance to the selected coreset row
    const float* a = emb + (size_t)m * D_DIM;
    const float* b = cs + (size_t)i * D_DIM;
    float s = 0.f;
#pragma unroll
    for (int t = 0; t < D_DIM / 64; ++t) {
        float d = a[lane + t * 64] - b[lane + t * 64];
        s += d * d;
    }
#pragma unroll
    for (int mk = 1; mk <= 32; mk <<= 1) s += __shfl_xor(s, mk, 64);
    if (lane == 0) {
        float sc = sqrtf(s);
        scores[m] = sc;
        loc[m] = i;
        int bb = m / P_PATCH, p = m % P_PATCH;
        unsigned long long key =
            ((unsigned long long)__float_as_uint(sc) << 32) |
            (unsigned)(0x7fffffff - p);
        atomicMax(&packed[bb], key);
    }
}

// -------------------- d_nn: 8 queries x 16384 coreset (coalesced GEMV) ----
__global__ void dnn_kernel(const float* __restrict__ cs,
                           const float* __restrict__ cnorm,
                           const unsigned long long* __restrict__ packed,
                           const int* __restrict__ loc,
                           float* __restrict__ dmat) {
    int lane = threadIdx.x & 63;
    int gw = (blockIdx.x * 256 + threadIdx.x) >> 6;  // 0..1023
    float qv[BATCH][6];
#pragma unroll
    for (int b = 0; b < BATCH; ++b) {
        int p  = 0x7fffffff - (unsigned)(packed[b] & 0xffffffffull);
        int nn = loc[b * P_PATCH + p];
        const float* qr = cs + (size_t)nn * D_DIM + lane * 6;
#pragma unroll
        for (int j = 0; j < 6; ++j) qv[b][j] = qr[j];
    }
    for (int n = gw; n < N_CS; n += 1024) {
        const float* r = cs + (size_t)n * D_DIM + lane * 6;
        float x[6];
#pragma unroll
        for (int j = 0; j < 6; ++j) x[j] = r[j];
        float s[BATCH];
#pragma unroll
        for (int b = 0; b < BATCH; ++b) {
            float t = 0.f;
#pragma unroll
            for (int j = 0; j < 6; ++j) t += x[j] * qv[b][j];
            s[b] = t;
        }
#pragma unroll
        for (int b = 0; b < BATCH; ++b)
#pragma unroll
            for (int mk = 1; mk <= 32; mk <<= 1) s[b] += __shfl_xor(s[b], mk, 64);
        if (lane < BATCH) {
            float sv = s[0];
#pragma unroll
            for (int b = 1; b < BATCH; ++b) sv = (lane == b) ? s[b] : sv;
            dmat[(size_t)lane * N_CS + n] = cnorm[n] - 2.f * sv;  // -qnorm shift: order-safe
        }
    }
}

// ----------------------- top-9 merge + exact dsup + softmax weighting ----
__device__ inline void merge9(float* av, int* ai, const float* bv, const int* bi) {
    float mv[KNN]; int mi[KNN];
    int x = 0, y = 0;
#pragma unroll
    for (int k = 0; k < KNN; ++k) {
        bool ta = (av[x] < bv[y]) || (av[x] == bv[y] && ai[x] < bi[y]);
        if (ta) { mv[k] = av[x]; mi[k] = ai[x]; ++x; }
        else    { mv[k] = bv[y]; mi[k] = bi[y]; ++y; }
    }
#pragma unroll
    for (int k = 0; k < KNN; ++k) { av[k] = mv[k]; ai[k] = mi[k]; }
}

__global__ void top9_final_kernel(const float* __restrict__ dmat,
                                  const float* __restrict__ emb,
                                  const float* __restrict__ cs,
                                  const unsigned long long* __restrict__ packed,
                                  float* __restrict__ out) {
    int b = blockIdx.x;
    int tid = threadIdx.x;  // 512
    __shared__ float lv[512][KNN];
    __shared__ int   li[512][KNN];
    __shared__ float mf[D_DIM];
    __shared__ float dsup[KNN];

    unsigned long long key = packed[b];
    int   mp     = 0x7fffffff - (unsigned)(key & 0xffffffffull);
    float bscore = __uint_as_float((unsigned)(key >> 32));
    const float* frow = emb + (size_t)(b * P_PATCH + mp) * D_DIM;
    for (int i = tid; i < D_DIM; i += 512) mf[i] = frow[i];

    float tv[KNN]; int ti[KNN];
#pragma unroll
    for (int k = 0; k < KNN; ++k) { tv[k] = 3.4e38f; ti[k] = 0x7fffffff; }
    for (int n = tid; n < N_CS; n += 512) {   // ascending n per thread
        float d = dmat[(size_t)b * N_CS + n];
        if (d < tv[KNN - 1] || (d == tv[KNN - 1] && n < ti[KNN - 1])) {
            tv[KNN - 1] = d; ti[KNN - 1] = n;
#pragma unroll
            for (int k = KNN - 1; k > 0; --k) {
                if (tv[k] < tv[k - 1] || (tv[k] == tv[k - 1] && ti[k] < ti[k - 1])) {
                    float fv = tv[k]; tv[k] = tv[k - 1]; tv[k - 1] = fv;
                    int   iv = ti[k]; ti[k] = ti[k - 1]; ti[k - 1] = iv;
                }
            }
        }
    }
#pragma unroll
    for (int k = 0; k < KNN; ++k) { lv[tid][k] = tv[k]; li[tid][k] = ti[k]; }
    __syncthreads();
    for (int off = 256; off > 0; off >>= 1) {
        if (tid < off) {
            float av[KNN]; int ai[KNN]; float bv2[KNN]; int bi2[KNN];
#pragma unroll
            for (int k = 0; k < KNN; ++k) {
                av[k]  = lv[tid][k];        ai[k]  = li[tid][k];
                bv2[k] = lv[tid + off][k];  bi2[k] = li[tid + off][k];
            }
            merge9(av, ai, bv2, bi2);
#pragma unroll
            for (int k = 0; k < KNN; ++k) { lv[tid][k] = av[k]; li[tid][k] = ai[k]; }
        }
        __syncthreads();
    }
    // exact fp32 distances to the 9 support rows: 32 lanes per neighbor
    {
        int k      = tid >> 5;   // 0..15
        int lane32 = tid & 31;
        if (k < KNN) {
            int idx = li[0][k];
            const float* r = cs + (size_t)idx * D_DIM;
            float s = 0.f;
            for (int i = lane32; i < D_DIM; i += 32) {
                float df = mf[i] - r[i];
                s += df * df;
            }
#pragma unroll
            for (int mk = 1; mk <= 16; mk <<= 1) s += __shfl_xor(s, mk, 64);
            if (lane32 == 0) dsup[k] = sqrtf(fmaxf(s, 0.f));
        }
    }
    __syncthreads();
    if (tid == 0) {
        float mx = dsup[0];
        for (int k = 1; k < KNN; ++k) mx = fmaxf(mx, dsup[k]);
        float sum = 0.f, e0 = 0.f;
        for (int k = 0; k < KNN; ++k) {
            float e = expf(dsup[k] - mx);
            sum += e;
            if (k == 0) e0 = e;
        }
        out[b] = (1.f - e0 / sum) * bscore;
    }
}

// ------------------------------------------------------------- launcher ----
extern "C" void kernel_launch(void* const* d_in, const int* in_sizes, int n_in,
                              void* d_out, int out_size, void* d_ws, size_t ws_size,
                              hipStream_t stream) {
    (void)in_sizes; (void)n_in; (void)out_size; (void)ws_size;
    const float* emb = (const float*)d_in[0];
    const float* cs  = (const float*)d_in[1];
    float* out = (float*)d_out;

    // workspace layout
    char* p = (char*)d_ws;
    float* cnorm  = (float*)p;  p += (size_t)N_CS * 4;                     // 64 KB
    float* pvals  = (float*)p;  p += (size_t)M_TOTAL * NTILES2 * 4;        // 1.6 MB
    int*   pidx   = (int*)p;    p += (size_t)M_TOTAL * NTILES2 * 4;        // 1.6 MB
    float* scores = (float*)p;  p += (size_t)M_TOTAL * 4;
    int*   loc    = (int*)p;    p += (size_t)M_TOTAL * 4;
    p = (char*)(((size_t)p + 7) & ~(size_t)7);
    unsigned long long* packed = (unsigned long long*)p; p += BATCH * 8;
    float* dmat   = (float*)p;  p += (size_t)BATCH * N_CS * 4;             // 512 KB
    p = (char*)(((size_t)p + 15) & ~(size_t)15);
    _Float16* embh = (_Float16*)p; p += (size_t)M_TOTAL * D_DIM * 2;       // 4.8 MB
    _Float16* csh  = (_Float16*)p; p += (size_t)N_CS * D_DIM * 2;          // 12.6 MB

    {
        int rows = N_CS + M_TOTAL;
        convert_all_kernel<<<(rows + 3) / 4, 256, 0, stream>>>(emb, cs, embh, csh,
                                                               cnorm, packed);
    }
    mindist_mfma_kernel<<<MTILES * NTILES2, 256, 0, stream>>>(embh, csh, cnorm,
                                                              pvals, pidx);
    reduce_rescore_kernel<<<M_TOTAL / 4, 256, 0, stream>>>(pvals, pidx, emb, cs,
                                                           scores, loc, packed);
    dnn_kernel<<<256, 256, 0, stream>>>(cs, cnorm, packed, loc, dmat);
    top9_final_kernel<<<BATCH, 512, 0, stream>>>(dmat, emb, cs, packed, out);
}

// Round 8
// 295.442 us; speedup vs baseline: 2.8076x; 1.2252x over previous
//
#include <hip/hip_runtime.h>
#include <hip/hip_bf16.h>
#include <math.h>

// Problem constants (fixed by setup_inputs)
#define M_TOTAL 6272   // B*P
#define N_CS    16384  // coreset rows
#define D_DIM   384
#define BATCH   8
#define P_PATCH 784
#define KNN     9

// MFMA GEMM tiling: 128x256 tile, 4 waves (2x2 of 64x128), BK=32
#define MTILES  (M_TOTAL / 128)  // 49
#define NTILES2 (N_CS / 256)     // 64 -> pvals[m][64]
#define NBLK    (M_TOTAL / 4)    // 1568 reduce blocks; 784=4*196 -> one batch/block
#define PBB     196              // partial entries per batch

typedef _Float16 half8 __attribute__((ext_vector_type(8)));
typedef float    floatx4 __attribute__((ext_vector_type(4)));

// async global->LDS, 16B per lane; LDS dest must be uniform-base + lane*16
__device__ __forceinline__ void async_copy16(const void* g, void* l) {
    __builtin_amdgcn_global_load_lds(
        (const __attribute__((address_space(1))) void*)g,
        (__attribute__((address_space(3))) void*)l, 16, 0, 0);
}

__device__ __forceinline__ unsigned long long shfl_xor_u64(unsigned long long v, int mk) {
    int lo = __shfl_xor((int)(unsigned)v, mk, 64);
    int hi = __shfl_xor((int)(unsigned)(v >> 32), mk, 64);
    return ((unsigned long long)(unsigned)hi << 32) | (unsigned)lo;
}

// ---------------- convert fp32->f16, fused cs+emb (wave per row) ----------
__global__ void convert_all_kernel(const float* __restrict__ emb,
                                   const float* __restrict__ cs,
                                   _Float16* __restrict__ embh,
                                   _Float16* __restrict__ csh,
                                   float* __restrict__ cnorm) {
    int w = threadIdx.x >> 6, lane = threadIdx.x & 63;
    int row = blockIdx.x * 4 + w;
    if (row >= N_CS + M_TOTAL) return;
    bool is_cs = row < N_CS;
    const float* r = (is_cs ? cs + (size_t)row * D_DIM
                            : emb + (size_t)(row - N_CS) * D_DIM) + lane * 6;
    float2 a = *(const float2*)r;
    float2 b = *(const float2*)(r + 2);
    float2 c = *(const float2*)(r + 4);
    union { _Float16 h[2]; unsigned u; } p0, p1, p2;
    p0.h[0] = (_Float16)a.x; p0.h[1] = (_Float16)a.y;
    p1.h[0] = (_Float16)b.x; p1.h[1] = (_Float16)b.y;
    p2.h[0] = (_Float16)c.x; p2.h[1] = (_Float16)c.y;
    unsigned* dst = (unsigned*)(is_cs ? csh + (size_t)row * D_DIM
                                      : embh + (size_t)(row - N_CS) * D_DIM) + lane * 3;
    dst[0] = p0.u; dst[1] = p1.u; dst[2] = p2.u;
    if (is_cs) {
        float s = a.x * a.x + a.y * a.y + b.x * b.x + b.y * b.y + c.x * c.x + c.y * c.y;
#pragma unroll
        for (int mk = 1; mk <= 32; mk <<= 1) s += __shfl_xor(s, mk, 64);
        if (lane == 0) cnorm[row] = s;
    }
}

// --------------------------------------------- MFMA GEMM + min/argmin ----
// 1-D grid 3136; XCD-aware remap (R7: FETCH 191->25 MB). BK=32: LDS 24 KB
// -> 4 blocks/CU (VGPR=128-capped), vs 3 at BK=64. Swizzle: 16B chunk
// stored at position p holds global chunk p ^ ((row>>1)&3); every
// consecutive-8-lane group of a ds_read_b128 then covers all 32 banks.
// __launch_bounds__(256,2): DO NOT raise — R6 at (256,3) got 84 VGPR and
// spilled acc (WRITE 1.4 GB, 612 us).
__global__ __launch_bounds__(256, 2) void mindist_mfma_kernel(
    const _Float16* __restrict__ embh, const _Float16* __restrict__ csh,
    const float* __restrict__ cnorm,
    float* __restrict__ pvals, int* __restrict__ pidx) {
    __shared__ _Float16 As[128 * 32];   // 8 KB
    __shared__ _Float16 Bs[256 * 32];   // 16 KB

    const int b    = blockIdx.x;
    const int bx   = b >> 6;                               // 0..48
    const int by   = ((b & 7) << 3) | ((b >> 3) & 7);      // 0..63 (XCD-major)
    const int tid  = threadIdx.x;
    const int lane = tid & 63;
    const int w    = tid >> 6;
    const int wr   = w >> 1, wc = w & 1;
    const int row0  = bx * 128;
    const int cbase = by * 256;
    const int q   = lane >> 4;
    const int cl  = lane & 15;

    floatx4 acc[4][8];
#pragma unroll
    for (int mi = 0; mi < 4; ++mi)
#pragma unroll
        for (int nj = 0; nj < 8; ++nj) acc[mi][nj] = (floatx4){0.f, 0.f, 0.f, 0.f};

    float cn_l[8];
#pragma unroll
    for (int nj = 0; nj < 8; ++nj)
        cn_l[nj] = cnorm[cbase + wc * 128 + nj * 16 + cl];

    const int sub4 = lane >> 2;         // row within 16-row staging block
    const int ch   = lane & 3;          // dest 16B chunk

    for (int kk = 0; kk < D_DIM; kk += 32) {
        __syncthreads();
#pragma unroll
        for (int i = 0; i < 6; ++i) {
            int inst = w * 6 + i;       // wave-uniform: 0..23 (8 A + 16 B)
            if (inst < 8) {
                int r  = inst * 16 + sub4;
                int sc = (ch ^ ((r >> 1) & 3)) * 8;
                async_copy16(embh + (size_t)(row0 + r) * D_DIM + kk + sc,
                             &As[inst * 512 + lane * 8]);
            } else {
                int blk = inst - 8;
                int r   = blk * 16 + sub4;
                int sc  = (ch ^ ((r >> 1) & 3)) * 8;
                async_copy16(csh + (size_t)(cbase + r) * D_DIM + kk + sc,
                             &Bs[blk * 512 + lane * 8]);
            }
        }
        __syncthreads();
        {
            half8 af[4], bf[8];
#pragma unroll
            for (int mi = 0; mi < 4; ++mi) {
                int R = wr * 64 + mi * 16 + cl;
                af[mi] = *(const half8*)&As[R * 32 + ((q ^ ((R >> 1) & 3)) * 8)];
            }
#pragma unroll
            for (int nj = 0; nj < 8; ++nj) {
                int R = wc * 128 + nj * 16 + cl;
                bf[nj] = *(const half8*)&Bs[R * 32 + ((q ^ ((R >> 1) & 3)) * 8)];
            }
#pragma unroll
            for (int mi = 0; mi < 4; ++mi)
#pragma unroll
                for (int nj = 0; nj < 8; ++nj)
                    acc[mi][nj] = __builtin_amdgcn_mfma_f32_16x16x32_f16(
                        af[mi], bf[nj], acc[mi][nj], 0, 0, 0);
        }
    }

    // epilogue: per-row min/argmin over the 256-wide tile
    __syncthreads();
    float* smv = (float*)As;            // [128][2] (1 KB)
    int*   smi = (int*)(As + 512);      // 1 KB past smv

#pragma unroll
    for (int mi = 0; mi < 4; ++mi) {
#pragma unroll
        for (int r = 0; r < 4; ++r) {
            float v = 3.4e38f; int idx = 0x7fffffff;
#pragma unroll
            for (int nj = 0; nj < 8; ++nj) {   // ascending col per lane, strict <
                float d = cn_l[nj] - 2.f * acc[mi][nj][r];
                int   c = cbase + wc * 128 + nj * 16 + cl;
                if (d < v) { v = d; idx = c; }
            }
#pragma unroll
            for (int mk = 1; mk <= 8; mk <<= 1) {
                float v2 = __shfl_xor(v, mk, 64);
                int   i2 = __shfl_xor(idx, mk, 64);
                if (v2 < v || (v2 == v && i2 < idx)) { v = v2; idx = i2; }
            }
            if (cl == 0) {
                int rl = wr * 64 + mi * 16 + q * 4 + r;
                smv[rl * 2 + wc] = v;
                smi[rl * 2 + wc] = idx;
            }
        }
    }
    __syncthreads();
    if (tid < 128) {
        float v = smv[tid * 2];      int i = smi[tid * 2];
        float v1 = smv[tid * 2 + 1]; int i1 = smi[tid * 2 + 1];
        if (v1 < v) { v = v1; i = i1; }   // wc0 indices always < wc1 indices
        pvals[(size_t)(row0 + tid) * NTILES2 + by] = v;
        pidx[(size_t)(row0 + tid) * NTILES2 + by]  = i;
    }
}

// ---- partial-min reduce + EXACT fp32 rescore + block-level argmax -------
// partial[block] = max over the block's 4 rows of (score_bits<<32)|(~patch):
// NO atomics (R7: 1568 device atomicMax on one 64B line bounced across
// XCDs, ~65 us serialization). dnn/top9 re-scan the 12.5 KB array instead.
__global__ void reduce_rescore_kernel(const float* __restrict__ pvals,
                                      const int* __restrict__ pidx,
                                      const float* __restrict__ emb,
                                      const float* __restrict__ cs,
                                      int* __restrict__ loc,
                                      unsigned long long* __restrict__ partial) {
    __shared__ unsigned long long keys[4];
    int w = threadIdx.x >> 6, lane = threadIdx.x & 63;
    int m = blockIdx.x * 4 + w;
    float v = pvals[(size_t)m * NTILES2 + lane];
    int   i = pidx[(size_t)m * NTILES2 + lane];
#pragma unroll
    for (int mk = 1; mk <= 32; mk <<= 1) {
        float v2 = __shfl_xor(v, mk, 64);
        int   i2 = __shfl_xor(i, mk, 64);
        if (v2 < v || (v2 == v && i2 < i)) { v = v2; i = i2; }
    }
    // exact fp32 distance to the selected coreset row
    const float* a = emb + (size_t)m * D_DIM;
    const float* bp = cs + (size_t)i * D_DIM;
    float s = 0.f;
#pragma unroll
    for (int t = 0; t < D_DIM / 64; ++t) {
        float d = a[lane + t * 64] - bp[lane + t * 64];
        s += d * d;
    }
#pragma unroll
    for (int mk = 1; mk <= 32; mk <<= 1) s += __shfl_xor(s, mk, 64);
    if (lane == 0) {
        float sc = sqrtf(s);
        loc[m] = i;
        int p = m % P_PATCH;
        keys[w] = ((unsigned long long)__float_as_uint(sc) << 32) |
                  (unsigned)(0x7fffffff - p);
    }
    __syncthreads();
    if (threadIdx.x == 0) {
        unsigned long long k = keys[0];
        if (keys[1] > k) k = keys[1];
        if (keys[2] > k) k = keys[2];
        if (keys[3] > k) k = keys[3];
        partial[blockIdx.x] = k;
    }
}

// -------------------- d_nn: 8 queries x 16384 coreset (coalesced GEMV) ----
__global__ void dnn_kernel(const float* __restrict__ cs,
                           const float* __restrict__ cnorm,
                           const unsigned long long* __restrict__ partial,
                           const int* __restrict__ loc,
                           float* __restrict__ dmat) {
    __shared__ int bnnS[BATCH];
    {   // per-block argmax recompute: 32 lanes per batch over 196 entries
        int bb = threadIdx.x >> 5, l32 = threadIdx.x & 31;
        unsigned long long best = 0ull;
        for (int j = l32; j < PBB; j += 32) {
            unsigned long long k = partial[bb * PBB + j];
            if (k > best) best = k;
        }
#pragma unroll
        for (int mk = 1; mk <= 16; mk <<= 1) {
            unsigned long long o = shfl_xor_u64(best, mk);
            if (o > best) best = o;
        }
        if (l32 == 0) {
            int p = 0x7fffffff - (unsigned)(best & 0xffffffffull);
            bnnS[bb] = loc[bb * P_PATCH + p];
        }
    }
    __syncthreads();

    int lane = threadIdx.x & 63;
    int gw = (blockIdx.x * 256 + threadIdx.x) >> 6;  // 0..1023
    float qv[BATCH][6];
#pragma unroll
    for (int b = 0; b < BATCH; ++b) {
        const float* qr = cs + (size_t)bnnS[b] * D_DIM + lane * 6;
#pragma unroll
        for (int j = 0; j < 6; ++j) qv[b][j] = qr[j];
    }
    for (int n = gw; n < N_CS; n += 1024) {
        const float* r = cs + (size_t)n * D_DIM + lane * 6;
        float x[6];
#pragma unroll
        for (int j = 0; j < 6; ++j) x[j] = r[j];
        float s[BATCH];
#pragma unroll
        for (int b = 0; b < BATCH; ++b) {
            float t = 0.f;
#pragma unroll
            for (int j = 0; j < 6; ++j) t += x[j] * qv[b][j];
            s[b] = t;
        }
#pragma unroll
        for (int b = 0; b < BATCH; ++b)
#pragma unroll
            for (int mk = 1; mk <= 32; mk <<= 1) s[b] += __shfl_xor(s[b], mk, 64);
        if (lane < BATCH) {
            float sv = s[0];
#pragma unroll
            for (int b = 1; b < BATCH; ++b) sv = (lane == b) ? s[b] : sv;
            dmat[(size_t)lane * N_CS + n] = cnorm[n] - 2.f * sv;  // -qnorm shift: order-safe
        }
    }
}

// ----------------------- top-9 merge + exact dsup + softmax weighting ----
__device__ inline void merge9(float* av, int* ai, const float* bv, const int* bi) {
    float mv[KNN]; int mi[KNN];
    int x = 0, y = 0;
#pragma unroll
    for (int k = 0; k < KNN; ++k) {
        bool ta = (av[x] < bv[y]) || (av[x] == bv[y] && ai[x] < bi[y]);
        if (ta) { mv[k] = av[x]; mi[k] = ai[x]; ++x; }
        else    { mv[k] = bv[y]; mi[k] = bi[y]; ++y; }
    }
#pragma unroll
    for (int k = 0; k < KNN; ++k) { av[k] = mv[k]; ai[k] = mi[k]; }
}

__global__ void top9_final_kernel(const float* __restrict__ dmat,
                                  const float* __restrict__ emb,
                                  const float* __restrict__ cs,
                                  const unsigned long long* __restrict__ partial,
                                  float* __restrict__ out) {
    int b = blockIdx.x;
    int tid = threadIdx.x;  // 512
    __shared__ float lv[512][KNN];
    __shared__ int   li[512][KNN];
    __shared__ float mf[D_DIM];
    __shared__ float dsup[KNN];
    __shared__ float bscoreS;
    __shared__ int   bpatchS;

    if (tid < 64) {  // argmax recompute for this batch
        unsigned long long best = 0ull;
        for (int j = tid; j < PBB; j += 64) {
            unsigned long long k = partial[b * PBB + j];
            if (k > best) best = k;
        }
#pragma unroll
        for (int mk = 1; mk <= 32; mk <<= 1) {
            unsigned long long o = shfl_xor_u64(best, mk);
            if (o > best) best = o;
        }
        if (tid == 0) {
            bpatchS = 0x7fffffff - (unsigned)(best & 0xffffffffull);
            bscoreS = __uint_as_float((unsigned)(best >> 32));
        }
    }
    __syncthreads();
    int mp = bpatchS;
    const float* frow = emb + (size_t)(b * P_PATCH + mp) * D_DIM;
    for (int i = tid; i < D_DIM; i += 512) mf[i] = frow[i];

    float tv[KNN]; int ti[KNN];
#pragma unroll
    for (int k = 0; k < KNN; ++k) { tv[k] = 3.4e38f; ti[k] = 0x7fffffff; }
    for (int n = tid; n < N_CS; n += 512) {   // ascending n per thread
        float d = dmat[(size_t)b * N_CS + n];
        if (d < tv[KNN - 1] || (d == tv[KNN - 1] && n < ti[KNN - 1])) {
            tv[KNN - 1] = d; ti[KNN - 1] = n;
#pragma unroll
            for (int k = KNN - 1; k > 0; --k) {
                if (tv[k] < tv[k - 1] || (tv[k] == tv[k - 1] && ti[k] < ti[k - 1])) {
                    float fv = tv[k]; tv[k] = tv[k - 1]; tv[k - 1] = fv;
                    int   iv = ti[k]; ti[k] = ti[k - 1]; ti[k - 1] = iv;
                }
            }
        }
    }
#pragma unroll
    for (int k = 0; k < KNN; ++k) { lv[tid][k] = tv[k]; li[tid][k] = ti[k]; }
    __syncthreads();
    for (int off = 256; off > 0; off >>= 1) {
        if (tid < off) {
            float av[KNN]; int ai[KNN]; float bv2[KNN]; int bi2[KNN];
#pragma unroll
            for (int k = 0; k < KNN; ++k) {
                av[k]  = lv[tid][k];        ai[k]  = li[tid][k];
                bv2[k] = lv[tid + off][k];  bi2[k] = li[tid + off][k];
            }
            merge9(av, ai, bv2, bi2);
#pragma unroll
            for (int k = 0; k < KNN; ++k) { lv[tid][k] = av[k]; li[tid][k] = ai[k]; }
        }
        __syncthreads();
    }
    // exact fp32 distances to the 9 support rows: 32 lanes per neighbor
    {
        int k      = tid >> 5;   // 0..15
        int lane32 = tid & 31;
        if (k < KNN) {
            int idx = li[0][k];
            const float* r = cs + (size_t)idx * D_DIM;
            float s = 0.f;
            for (int i = lane32; i < D_DIM; i += 32) {
                float df = mf[i] - r[i];
                s += df * df;
            }
#pragma unroll
            for (int mk = 1; mk <= 16; mk <<= 1) s += __shfl_xor(s, mk, 64);
            if (lane32 == 0) dsup[k] = sqrtf(fmaxf(s, 0.f));
        }
    }
    __syncthreads();
    if (tid == 0) {
        float mx = dsup[0];
        for (int k = 1; k < KNN; ++k) mx = fmaxf(mx, dsup[k]);
        float sum = 0.f, e0 = 0.f;
        for (int k = 0; k < KNN; ++k) {
            float e = expf(dsup[k] - mx);
            sum += e;
            if (k == 0) e0 = e;
        }
        out[b] = (1.f - e0 / sum) * bscoreS;
    }
}

// ------------------------------------------------------------- launcher ----
extern "C" void kernel_launch(void* const* d_in, const int* in_sizes, int n_in,
                              void* d_out, int out_size, void* d_ws, size_t ws_size,
                              hipStream_t stream) {
    (void)in_sizes; (void)n_in; (void)out_size; (void)ws_size;
    const float* emb = (const float*)d_in[0];
    const float* cs  = (const float*)d_in[1];
    float* out = (float*)d_out;

    // workspace layout
    char* p = (char*)d_ws;
    float* cnorm  = (float*)p;  p += (size_t)N_CS * 4;                     // 64 KB
    float* pvals  = (float*)p;  p += (size_t)M_TOTAL * NTILES2 * 4;        // 1.6 MB
    int*   pidx   = (int*)p;    p += (size_t)M_TOTAL * NTILES2 * 4;        // 1.6 MB
    int*   loc    = (int*)p;    p += (size_t)M_TOTAL * 4;
    p = (char*)(((size_t)p + 7) & ~(size_t)7);
    unsigned long long* partial = (unsigned long long*)p; p += NBLK * 8;   // 12.5 KB
    float* dmat   = (float*)p;  p += (size_t)BATCH * N_CS * 4;             // 512 KB
    p = (char*)(((size_t)p + 15) & ~(size_t)15);
    _Float16* embh = (_Float16*)p; p += (size_t)M_TOTAL * D_DIM * 2;       // 4.8 MB
    _Float16* csh  = (_Float16*)p; p += (size_t)N_CS * D_DIM * 2;          // 12.6 MB

    {
        int rows = N_CS + M_TOTAL;
        convert_all_kernel<<<(rows + 3) / 4, 256, 0, stream>>>(emb, cs, embh, csh, cnorm);
    }
    mindist_mfma_kernel<<<MTILES * NTILES2, 256, 0, stream>>>(embh, csh, cnorm,
                                                              pvals, pidx);
    reduce_rescore_kernel<<<NBLK, 256, 0, stream>>>(pvals, pidx, emb, cs, loc, partial);
    dnn_kernel<<<256, 256, 0, stream>>>(cs, cnorm, partial, loc, dmat);
    top9_final_kernel<<<BATCH, 512, 0, stream>>>(dmat, emb, cs, partial, out);
}

// Round 9
// 284.833 us; speedup vs baseline: 2.9121x; 1.0372x over previous
//
#include <hip/hip_runtime.h>
#include <hip/hip_bf16.h>
#include <math.h>

// Problem constants (fixed by setup_inputs)
#define M_TOTAL 6272   // B*P
#define N_CS    16384  // coreset rows
#define D_DIM   384
#define BATCH   8
#define P_PATCH 784
#define KNN     9

// MFMA GEMM tiling: 128x256 tile, 4 waves (2x2 of 64x128), BK=32, dbuf
#define MTILES  (M_TOTAL / 128)  // 49
#define NTILES2 (N_CS / 256)     // 64 -> pvals[m][64]
#define NBLK    (M_TOTAL / 4)    // 1568 reduce blocks; 784=4*196 -> one batch/block
#define PBB     196              // partial entries per batch

typedef _Float16 half8 __attribute__((ext_vector_type(8)));
typedef float    floatx4 __attribute__((ext_vector_type(4)));

// async global->LDS, 16B per lane; LDS dest must be uniform-base + lane*16
__device__ __forceinline__ void async_copy16(const void* g, void* l) {
    __builtin_amdgcn_global_load_lds(
        (const __attribute__((address_space(1))) void*)g,
        (__attribute__((address_space(3))) void*)l, 16, 0, 0);
}

__device__ __forceinline__ unsigned long long shfl_xor_u64(unsigned long long v, int mk) {
    int lo = __shfl_xor((int)(unsigned)v, mk, 64);
    int hi = __shfl_xor((int)(unsigned)(v >> 32), mk, 64);
    return ((unsigned long long)(unsigned)hi << 32) | (unsigned)lo;
}

// ---------------- convert fp32->f16, fused cs+emb (wave per row) ----------
__global__ void convert_all_kernel(const float* __restrict__ emb,
                                   const float* __restrict__ cs,
                                   _Float16* __restrict__ embh,
                                   _Float16* __restrict__ csh,
                                   float* __restrict__ cnorm) {
    int w = threadIdx.x >> 6, lane = threadIdx.x & 63;
    int row = blockIdx.x * 4 + w;
    if (row >= N_CS + M_TOTAL) return;
    bool is_cs = row < N_CS;
    const float* r = (is_cs ? cs + (size_t)row * D_DIM
                            : emb + (size_t)(row - N_CS) * D_DIM) + lane * 6;
    float2 a = *(const float2*)r;
    float2 b = *(const float2*)(r + 2);
    float2 c = *(const float2*)(r + 4);
    union { _Float16 h[2]; unsigned u; } p0, p1, p2;
    p0.h[0] = (_Float16)a.x; p0.h[1] = (_Float16)a.y;
    p1.h[0] = (_Float16)b.x; p1.h[1] = (_Float16)b.y;
    p2.h[0] = (_Float16)c.x; p2.h[1] = (_Float16)c.y;
    unsigned* dst = (unsigned*)(is_cs ? csh + (size_t)row * D_DIM
                                      : embh + (size_t)(row - N_CS) * D_DIM) + lane * 3;
    dst[0] = p0.u; dst[1] = p1.u; dst[2] = p2.u;
    if (is_cs) {
        float s = a.x * a.x + a.y * a.y + b.x * b.x + b.y * b.y + c.x * c.x + c.y * c.y;
#pragma unroll
        for (int mk = 1; mk <= 32; mk <<= 1) s += __shfl_xor(s, mk, 64);
        if (lane == 0) cnorm[row] = s;
    }
}

// --------------------------------------------- MFMA GEMM + min/argmin ----
// 1-D grid 3136; XCD-aware remap (R7: FETCH 191->25 MB). BK=32.
// R9: double-buffered K-loop with loads issued AFTER the drain barrier:
// the compiler's vmcnt(0)-before-s_barrier then waits on loads that have
// had a full compute phase in flight. Four DISTINCT __shared__ arrays so
// alias analysis can't insert a defensive vmcnt before the ds_reads.
// __launch_bounds__(256,2): DO NOT raise — R6 at (256,3) got 84 VGPR and
// spilled acc (WRITE 1.4 GB, 612 us).
__global__ __launch_bounds__(256, 2) void mindist_mfma_kernel(
    const _Float16* __restrict__ embh, const _Float16* __restrict__ csh,
    const float* __restrict__ cnorm,
    float* __restrict__ pvals, int* __restrict__ pidx) {
    __shared__ _Float16 As0[128 * 32];   // 8 KB
    __shared__ _Float16 As1[128 * 32];   // 8 KB
    __shared__ _Float16 Bs0[256 * 32];   // 16 KB
    __shared__ _Float16 Bs1[256 * 32];   // 16 KB

    const int b    = blockIdx.x;
    const int bx   = b >> 6;                               // 0..48
    const int by   = ((b & 7) << 3) | ((b >> 3) & 7);      // 0..63 (XCD-major)
    const int tid  = threadIdx.x;
    const int lane = tid & 63;
    const int w    = tid >> 6;
    const int wr   = w >> 1, wc = w & 1;
    const int row0  = bx * 128;
    const int cbase = by * 256;
    const int q   = lane >> 4;
    const int cl  = lane & 15;

    floatx4 acc[4][8];
#pragma unroll
    for (int mi = 0; mi < 4; ++mi)
#pragma unroll
        for (int nj = 0; nj < 8; ++nj) acc[mi][nj] = (floatx4){0.f, 0.f, 0.f, 0.f};

    float cn_l[8];
#pragma unroll
    for (int nj = 0; nj < 8; ++nj)
        cn_l[nj] = cnorm[cbase + wc * 128 + nj * 16 + cl];

    const int sub4 = lane >> 2;         // row within 16-row staging block
    const int ch   = lane & 3;          // dest 16B chunk

    // stage one BK=32 chunk (A 8 KB + B 16 KB) into (As,Bs)
#define STAGE(AS, BS, KK)                                                     \
    {                                                                         \
        _Pragma("unroll")                                                     \
        for (int i = 0; i < 6; ++i) {                                         \
            int inst = w * 6 + i;                                             \
            if (inst < 8) {                                                   \
                int r  = inst * 16 + sub4;                                    \
                int sc = (ch ^ ((r >> 1) & 3)) * 8;                           \
                async_copy16(embh + (size_t)(row0 + r) * D_DIM + (KK) + sc,   \
                             &AS[inst * 512 + lane * 8]);                     \
            } else {                                                          \
                int blk = inst - 8;                                           \
                int r   = blk * 16 + sub4;                                    \
                int sc  = (ch ^ ((r >> 1) & 3)) * 8;                          \
                async_copy16(csh + (size_t)(cbase + r) * D_DIM + (KK) + sc,   \
                             &BS[blk * 512 + lane * 8]);                      \
            }                                                                 \
        }                                                                     \
    }

#define COMPUTE(AS, BS)                                                       \
    {                                                                         \
        half8 af[4], bf[8];                                                   \
        _Pragma("unroll")                                                     \
        for (int mi = 0; mi < 4; ++mi) {                                      \
            int R = wr * 64 + mi * 16 + cl;                                   \
            af[mi] = *(const half8*)&AS[R * 32 + ((q ^ ((R >> 1) & 3)) * 8)]; \
        }                                                                     \
        _Pragma("unroll")                                                     \
        for (int nj = 0; nj < 8; ++nj) {                                      \
            int R = wc * 128 + nj * 16 + cl;                                  \
            bf[nj] = *(const half8*)&BS[R * 32 + ((q ^ ((R >> 1) & 3)) * 8)]; \
        }                                                                     \
        _Pragma("unroll")                                                     \
        for (int mi = 0; mi < 4; ++mi)                                        \
            _Pragma("unroll")                                                 \
            for (int nj = 0; nj < 8; ++nj)                                    \
                acc[mi][nj] = __builtin_amdgcn_mfma_f32_16x16x32_f16(         \
                    af[mi], bf[nj], acc[mi][nj], 0, 0, 0);                    \
    }

    // 12 chunks of K=32. Pipeline: buf0 pre-staged; each phase:
    // barrier (drains CURRENT buf's loads, certifies other buf free) ->
    // issue NEXT chunk into other buf -> compute current buf.
    STAGE(As0, Bs0, 0);
    int kk = 0;
#pragma unroll 1
    for (int jj = 0; jj < 5; ++jj) {
        __syncthreads();                 // drain chunk kk (buf0)
        STAGE(As1, Bs1, kk + 32);        // prefetch: flies during compute
        COMPUTE(As0, Bs0);
        __syncthreads();                 // drain chunk kk+32 (buf1)
        STAGE(As0, Bs0, kk + 64);
        COMPUTE(As1, Bs1);
        kk += 64;
    }
    // kk = 320: chunks 320, 352 remain
    __syncthreads();
    STAGE(As1, Bs1, kk + 32);
    COMPUTE(As0, Bs0);
    __syncthreads();
    COMPUTE(As1, Bs1);
#undef STAGE
#undef COMPUTE

    // epilogue: per-row min/argmin over the 256-wide tile
    __syncthreads();
    float* smv = (float*)As0;           // [128][2] (1 KB)
    int*   smi = (int*)(As0 + 512);     // 1 KB past smv

#pragma unroll
    for (int mi = 0; mi < 4; ++mi) {
#pragma unroll
        for (int r = 0; r < 4; ++r) {
            float v = 3.4e38f; int idx = 0x7fffffff;
#pragma unroll
            for (int nj = 0; nj < 8; ++nj) {   // ascending col per lane, strict <
                float d = cn_l[nj] - 2.f * acc[mi][nj][r];
                int   c = cbase + wc * 128 + nj * 16 + cl;
                if (d < v) { v = d; idx = c; }
            }
#pragma unroll
            for (int mk = 1; mk <= 8; mk <<= 1) {
                float v2 = __shfl_xor(v, mk, 64);
                int   i2 = __shfl_xor(idx, mk, 64);
                if (v2 < v || (v2 == v && i2 < idx)) { v = v2; idx = i2; }
            }
            if (cl == 0) {
                int rl = wr * 64 + mi * 16 + q * 4 + r;
                smv[rl * 2 + wc] = v;
                smi[rl * 2 + wc] = idx;
            }
        }
    }
    __syncthreads();
    if (tid < 128) {
        float v = smv[tid * 2];      int i = smi[tid * 2];
        float v1 = smv[tid * 2 + 1]; int i1 = smi[tid * 2 + 1];
        if (v1 < v) { v = v1; i = i1; }   // wc0 indices always < wc1 indices
        pvals[(size_t)(row0 + tid) * NTILES2 + by] = v;
        pidx[(size_t)(row0 + tid) * NTILES2 + by]  = i;
    }
}

// ---- partial-min reduce + EXACT fp32 rescore + block-level argmax -------
// partial[block] = max over the block's 4 rows of (score_bits<<32)|(~patch):
// NO atomics (R7: 1568 device atomicMax on one 64B line bounced across
// XCDs, ~65 us serialization). dnn/top9 re-scan the 12.5 KB array instead.
__global__ void reduce_rescore_kernel(const float* __restrict__ pvals,
                                      const int* __restrict__ pidx,
                                      const float* __restrict__ emb,
                                      const float* __restrict__ cs,
                                      int* __restrict__ loc,
                                      unsigned long long* __restrict__ partial) {
    __shared__ unsigned long long keys[4];
    int w = threadIdx.x >> 6, lane = threadIdx.x & 63;
    int m = blockIdx.x * 4 + w;
    float v = pvals[(size_t)m * NTILES2 + lane];
    int   i = pidx[(size_t)m * NTILES2 + lane];
#pragma unroll
    for (int mk = 1; mk <= 32; mk <<= 1) {
        float v2 = __shfl_xor(v, mk, 64);
        int   i2 = __shfl_xor(i, mk, 64);
        if (v2 < v || (v2 == v && i2 < i)) { v = v2; i = i2; }
    }
    // exact fp32 distance to the selected coreset row
    const float* a = emb + (size_t)m * D_DIM;
    const float* bp = cs + (size_t)i * D_DIM;
    float s = 0.f;
#pragma unroll
    for (int t = 0; t < D_DIM / 64; ++t) {
        float d = a[lane + t * 64] - bp[lane + t * 64];
        s += d * d;
    }
#pragma unroll
    for (int mk = 1; mk <= 32; mk <<= 1) s += __shfl_xor(s, mk, 64);
    if (lane == 0) {
        float sc = sqrtf(s);
        loc[m] = i;
        int p = m % P_PATCH;
        keys[w] = ((unsigned long long)__float_as_uint(sc) << 32) |
                  (unsigned)(0x7fffffff - p);
    }
    __syncthreads();
    if (threadIdx.x == 0) {
        unsigned long long k = keys[0];
        if (keys[1] > k) k = keys[1];
        if (keys[2] > k) k = keys[2];
        if (keys[3] > k) k = keys[3];
        partial[blockIdx.x] = k;
    }
}

// -------------------- d_nn: 8 queries x 16384 coreset (coalesced GEMV) ----
__global__ void dnn_kernel(const float* __restrict__ cs,
                           const float* __restrict__ cnorm,
                           const unsigned long long* __restrict__ partial,
                           const int* __restrict__ loc,
                           float* __restrict__ dmat) {
    __shared__ int bnnS[BATCH];
    {   // per-block argmax recompute: 32 lanes per batch over 196 entries
        int bb = threadIdx.x >> 5, l32 = threadIdx.x & 31;
        unsigned long long best = 0ull;
        for (int j = l32; j < PBB; j += 32) {
            unsigned long long k = partial[bb * PBB + j];
            if (k > best) best = k;
        }
#pragma unroll
        for (int mk = 1; mk <= 16; mk <<= 1) {
            unsigned long long o = shfl_xor_u64(best, mk);
            if (o > best) best = o;
        }
        if (l32 == 0) {
            int p = 0x7fffffff - (unsigned)(best & 0xffffffffull);
            bnnS[bb] = loc[bb * P_PATCH + p];
        }
    }
    __syncthreads();

    int lane = threadIdx.x & 63;
    int gw = (blockIdx.x * 256 + threadIdx.x) >> 6;  // 0..1023
    float qv[BATCH][6];
#pragma unroll
    for (int b = 0; b < BATCH; ++b) {
        const float* qr = cs + (size_t)bnnS[b] * D_DIM + lane * 6;
#pragma unroll
        for (int j = 0; j < 6; ++j) qv[b][j] = qr[j];
    }
    for (int n = gw; n < N_CS; n += 1024) {
        const float* r = cs + (size_t)n * D_DIM + lane * 6;
        float x[6];
#pragma unroll
        for (int j = 0; j < 6; ++j) x[j] = r[j];
        float s[BATCH];
#pragma unroll
        for (int b = 0; b < BATCH; ++b) {
            float t = 0.f;
#pragma unroll
            for (int j = 0; j < 6; ++j) t += x[j] * qv[b][j];
            s[b] = t;
        }
#pragma unroll
        for (int b = 0; b < BATCH; ++b)
#pragma unroll
            for (int mk = 1; mk <= 32; mk <<= 1) s[b] += __shfl_xor(s[b], mk, 64);
        if (lane < BATCH) {
            float sv = s[0];
#pragma unroll
            for (int b = 1; b < BATCH; ++b) sv = (lane == b) ? s[b] : sv;
            dmat[(size_t)lane * N_CS + n] = cnorm[n] - 2.f * sv;  // -qnorm shift: order-safe
        }
    }
}

// ----------------------- top-9 merge + exact dsup + softmax weighting ----
__device__ inline void merge9(float* av, int* ai, const float* bv, const int* bi) {
    float mv[KNN]; int mi[KNN];
    int x = 0, y = 0;
#pragma unroll
    for (int k = 0; k < KNN; ++k) {
        bool ta = (av[x] < bv[y]) || (av[x] == bv[y] && ai[x] < bi[y]);
        if (ta) { mv[k] = av[x]; mi[k] = ai[x]; ++x; }
        else    { mv[k] = bv[y]; mi[k] = bi[y]; ++y; }
    }
#pragma unroll
    for (int k = 0; k < KNN; ++k) { av[k] = mv[k]; ai[k] = mi[k]; }
}

__global__ void top9_final_kernel(const float* __restrict__ dmat,
                                  const float* __restrict__ emb,
                                  const float* __restrict__ cs,
                                  const unsigned long long* __restrict__ partial,
                                  float* __restrict__ out) {
    int b = blockIdx.x;
    int tid = threadIdx.x;  // 512
    __shared__ float lv[512][KNN];
    __shared__ int   li[512][KNN];
    __shared__ float mf[D_DIM];
    __shared__ float dsup[KNN];
    __shared__ float bscoreS;
    __shared__ int   bpatchS;

    if (tid < 64) {  // argmax recompute for this batch
        unsigned long long best = 0ull;
        for (int j = tid; j < PBB; j += 64) {
            unsigned long long k = partial[b * PBB + j];
            if (k > best) best = k;
        }
#pragma unroll
        for (int mk = 1; mk <= 32; mk <<= 1) {
            unsigned long long o = shfl_xor_u64(best, mk);
            if (o > best) best = o;
        }
        if (tid == 0) {
            bpatchS = 0x7fffffff - (unsigned)(best & 0xffffffffull);
            bscoreS = __uint_as_float((unsigned)(best >> 32));
        }
    }
    __syncthreads();
    int mp = bpatchS;
    const float* frow = emb + (size_t)(b * P_PATCH + mp) * D_DIM;
    for (int i = tid; i < D_DIM; i += 512) mf[i] = frow[i];

    float tv[KNN]; int ti[KNN];
#pragma unroll
    for (int k = 0; k < KNN; ++k) { tv[k] = 3.4e38f; ti[k] = 0x7fffffff; }
    for (int n = tid; n < N_CS; n += 512) {   // ascending n per thread
        float d = dmat[(size_t)b * N_CS + n];
        if (d < tv[KNN - 1] || (d == tv[KNN - 1] && n < ti[KNN - 1])) {
            tv[KNN - 1] = d; ti[KNN - 1] = n;
#pragma unroll
            for (int k = KNN - 1; k > 0; --k) {
                if (tv[k] < tv[k - 1] || (tv[k] == tv[k - 1] && ti[k] < ti[k - 1])) {
                    float fv = tv[k]; tv[k] = tv[k - 1]; tv[k - 1] = fv;
                    int   iv = ti[k]; ti[k] = ti[k - 1]; ti[k - 1] = iv;
                }
            }
        }
    }
#pragma unroll
    for (int k = 0; k < KNN; ++k) { lv[tid][k] = tv[k]; li[tid][k] = ti[k]; }
    __syncthreads();
    for (int off = 256; off > 0; off >>= 1) {
        if (tid < off) {
            float av[KNN]; int ai[KNN]; float bv2[KNN]; int bi2[KNN];
#pragma unroll
            for (int k = 0; k < KNN; ++k) {
                av[k]  = lv[tid][k];        ai[k]  = li[tid][k];
                bv2[k] = lv[tid + off][k];  bi2[k] = li[tid + off][k];
            }
            merge9(av, ai, bv2, bi2);
#pragma unroll
            for (int k = 0; k < KNN; ++k) { lv[tid][k] = av[k]; li[tid][k] = ai[k]; }
        }
        __syncthreads();
    }
    // exact fp32 distances to the 9 support rows: 32 lanes per neighbor
    {
        int k      = tid >> 5;   // 0..15
        int lane32 = tid & 31;
        if (k < KNN) {
            int idx = li[0][k];
            const float* r = cs + (size_t)idx * D_DIM;
            float s = 0.f;
            for (int i = lane32; i < D_DIM; i += 32) {
                float df = mf[i] - r[i];
                s += df * df;
            }
#pragma unroll
            for (int mk = 1; mk <= 16; mk <<= 1) s += __shfl_xor(s, mk, 64);
            if (lane32 == 0) dsup[k] = sqrtf(fmaxf(s, 0.f));
        }
    }
    __syncthreads();
    if (tid == 0) {
        float mx = dsup[0];
        for (int k = 1; k < KNN; ++k) mx = fmaxf(mx, dsup[k]);
        float sum = 0.f, e0 = 0.f;
        for (int k = 0; k < KNN; ++k) {
            float e = expf(dsup[k] - mx);
            sum += e;
            if (k == 0) e0 = e;
        }
        out[b] = (1.f - e0 / sum) * bscoreS;
    }
}

// ------------------------------------------------------------- launcher ----
extern "C" void kernel_launch(void* const* d_in, const int* in_sizes, int n_in,
                              void* d_out, int out_size, void* d_ws, size_t ws_size,
                              hipStream_t stream) {
    (void)in_sizes; (void)n_in; (void)out_size; (void)ws_size;
    const float* emb = (const float*)d_in[0];
    const float* cs  = (const float*)d_in[1];
    float* out = (float*)d_out;

    // workspace layout
    char* p = (char*)d_ws;
    float* cnorm  = (float*)p;  p += (size_t)N_CS * 4;                     // 64 KB
    float* pvals  = (float*)p;  p += (size_t)M_TOTAL * NTILES2 * 4;        // 1.6 MB
    int*   pidx   = (int*)p;    p += (size_t)M_TOTAL * NTILES2 * 4;        // 1.6 MB
    int*   loc    = (int*)p;    p += (size_t)M_TOTAL * 4;
    p = (char*)(((size_t)p + 7) & ~(size_t)7);
    unsigned long long* partial = (unsigned long long*)p; p += NBLK * 8;   // 12.5 KB
    float* dmat   = (float*)p;  p += (size_t)BATCH * N_CS * 4;             // 512 KB
    p = (char*)(((size_t)p + 15) & ~(size_t)15);
    _Float16* embh = (_Float16*)p; p += (size_t)M_TOTAL * D_DIM * 2;       // 4.8 MB
    _Float16* csh  = (_Float16*)p; p += (size_t)N_CS * D_DIM * 2;          // 12.6 MB

    {
        int rows = N_CS + M_TOTAL;
        convert_all_kernel<<<(rows + 3) / 4, 256, 0, stream>>>(emb, cs, embh, csh, cnorm);
    }
    mindist_mfma_kernel<<<MTILES * NTILES2, 256, 0, stream>>>(embh, csh, cnorm,
                                                              pvals, pidx);
    reduce_rescore_kernel<<<NBLK, 256, 0, stream>>>(pvals, pidx, emb, cs, loc, partial);
    dnn_kernel<<<256, 256, 0, stream>>>(cs, cnorm, partial, loc, dmat);
    top9_final_kernel<<<BATCH, 512, 0, stream>>>(dmat, emb, cs, partial, out);
}